// Round 10
// baseline (356.495 us; speedup 1.0000x reference)
//
#include <hip/hip_runtime.h>

#define N_NODES 50000
#define N_EDGES 800000
#define ETOT (N_EDGES + N_NODES)
#define DIN 512
#define HID 256
#define NOUT 64
#define SCAN_CHUNK 2048

typedef __attribute__((ext_vector_type(8))) short short8;
typedef __attribute__((ext_vector_type(4))) float f32x4;
typedef __attribute__((ext_vector_type(2))) float f32x2;
typedef __attribute__((ext_vector_type(4))) unsigned short us4;
typedef __attribute__((ext_vector_type(4))) unsigned int u32x4;

#define FMA2(a, b, c) __builtin_elementwise_fma((a), (b), (c))

// float -> bf16 bits, round-to-nearest-even
__device__ __forceinline__ unsigned short f2bf(float f) {
  union { float f; unsigned u; } x; x.f = f;
  unsigned r = x.u + 0x7fff + ((x.u >> 16) & 1);
  return (unsigned short)(r >> 16);
}
__device__ __forceinline__ float bf2f(unsigned short b) {
  return __uint_as_float(((unsigned)b) << 16);
}
// u32 holding bf16 pair {elem 2k (lo), elem 2k+1 (hi)} -> float2, 2 VALU ops
__device__ __forceinline__ f32x2 bfpair(unsigned u) {
  f32x2 r;
  r.x = __uint_as_float(u << 16);
  r.y = __uint_as_float(u & 0xffff0000u);
  return r;
}
// packed RNE convert: {lo: bf16(a), hi: bf16(b)} in one VALU inst
__device__ __forceinline__ unsigned cvtpk(float a, float b) {
  unsigned r;
  asm("v_cvt_pk_bf16_f32 %0, %1, %2" : "=v"(r) : "v"(a), "v"(b));
  return r;
}

// address-space casts for global_load_lds
#define AS1(p) ((const __attribute__((address_space(1))) unsigned int*)(p))
#define AS3(p) ((__attribute__((address_space(3))) unsigned int*)(p))

// ---------------- edge index decode (int32 vs int64 hedge) ----------------
__device__ __forceinline__ int edge_at(const void* ei, long long idx, int is32) {
  if (is32) return ((const int*)ei)[idx];
  return (int)((const long long*)ei)[idx];
}

// cursor[i]=1 + dtype detect + w1 -> bf16 + w2 -> bf16-pair table.
__global__ void initK(const void* ei, int* cursor, int* flag,
                      const float* __restrict__ w1, unsigned short* __restrict__ wb,
                      const float* __restrict__ w2, unsigned* __restrict__ w2b) {
  int i = blockIdx.x * blockDim.x + threadIdx.x;
  if (i < N_NODES) cursor[i] = 1;
  if (i < (HID * DIN) / 8) {  // 16384 chunks of 8 floats
    const float* src = w1 + i * 8;
    float4 v0 = ((const float4*)src)[0];
    float4 v1 = ((const float4*)src)[1];
    short8 s;
    s[0] = f2bf(v0.x); s[1] = f2bf(v0.y); s[2] = f2bf(v0.z); s[3] = f2bf(v0.w);
    s[4] = f2bf(v1.x); s[5] = f2bf(v1.y); s[6] = f2bf(v1.z); s[7] = f2bf(v1.w);
    *(short8*)(wb + i * 8) = s;
  }
  if (i < (NOUT * HID) / 2) {  // 8192 bf16 pairs of w2
    int c = i >> 7, kp = i & 127;
    const float* wr = w2 + c * HID + kp * 2;
    unsigned lo = f2bf(wr[0]);
    unsigned hi = f2bf(wr[1]);
    w2b[i] = lo | (hi << 16);
  }
  if (blockIdx.x == 0 && threadIdx.x < 64) {
    int lane = threadIdx.x;
    bool bad = false;
#pragma unroll
    for (int j = 0; j < 32; ++j) {
      long long v = ((const long long*)ei)[lane * 32 + j];
      bad |= (v < 0 || v >= N_NODES);
    }
    bool anybad = __any(bad);
    if (lane == 0) *flag = anybad ? 1 : 0;
  }
}

__global__ void histK(const void* ei, const int* flag, int* cursor) {
  int e = blockIdx.x * blockDim.x + threadIdx.x;
  if (e >= N_EDGES) return;
  int f = *flag;
  int d = edge_at(ei, (long long)N_EDGES + e, f);
  atomicAdd(&cursor[d], 1);
}

// ---------------- exclusive scan over counts -> row_ptr ----------------
__global__ void scan1K(const int* counts, int* excl, int* bsums) {
  __shared__ int sdata[256];
  int base = blockIdx.x * SCAN_CHUNK;
  int t = threadIdx.x;
  int local[8];
  int sum = 0;
#pragma unroll
  for (int j = 0; j < 8; ++j) {
    int idx = base + t * 8 + j;
    int v = (idx < N_NODES) ? counts[idx] : 0;
    local[j] = sum;
    sum += v;
  }
  sdata[t] = sum;
  __syncthreads();
  for (int off = 1; off < 256; off <<= 1) {
    int v = (t >= off) ? sdata[t - off] : 0;
    __syncthreads();
    sdata[t] += v;
    __syncthreads();
  }
  int texcl = (t == 0) ? 0 : sdata[t - 1];
#pragma unroll
  for (int j = 0; j < 8; ++j) {
    int idx = base + t * 8 + j;
    if (idx < N_NODES) excl[idx] = texcl + local[j];
  }
  if (t == 255) bsums[blockIdx.x] = sdata[255];
}

// scan3: add inline prefix of raw bsums (<=25 entries, wave-uniform loop).
__global__ void scan3K(int* row_ptr, const int* bsums, int* cursor) {
  int i = blockIdx.x * blockDim.x + threadIdx.x;
  if (i < N_NODES) {
    int nb = i >> 11;
    int pre = 0;
    for (int b = 0; b < nb; ++b) pre += bsums[b];
    int v = row_ptr[i] + pre;
    row_ptr[i] = v;
    cursor[i] = v;
    if (i == 0) row_ptr[N_NODES] = ETOT;
  }
}

__global__ void scatterK(const void* ei, const int* flag, int* cursor, int* col) {
  int e = blockIdx.x * blockDim.x + threadIdx.x;
  if (e < N_EDGES) {
    int f = *flag;
    int s = edge_at(ei, e, f);
    int d = edge_at(ei, (long long)N_EDGES + e, f);
    int pos = atomicAdd(&cursor[d], 1);
    col[pos] = s;
  } else if (e < N_EDGES + N_NODES) {
    int i = e - N_EDGES;
    int pos = atomicAdd(&cursor[i], 1);
    col[pos] = i;
  }
}

// ------- GEMM1: h_bf = bf16(relu(x @ w1^T + b1)) + fused row-norm ----------
// BM=64, BN=256 (grid.y=1: x fp32 read exactly once), BK=64, 4 waves, each
// owning a 64x64 column stripe. A fp32 rows = 256B = 16 slots, staged with
// pre-swizzled source slot^(r&7) (2-way read aliasing = free). B bf16 rows
// = 128B, 8 slots, slot=(kk*4+g)^(c&7) (r2-proven, 0 conflicts). Epilogue:
// fused invn of the bf16-rounded outputs (matches normBF numerics).
__global__ __launch_bounds__(256) void gemm1MF(const float* __restrict__ A,
                                               const unsigned short* __restrict__ Bb,
                                               const float* __restrict__ bias,
                                               unsigned short* __restrict__ C,
                                               float* __restrict__ invn) {
  __shared__ float As[64 * 64];    // 16 KB
  __shared__ short Bs[256 * 64];   // 32 KB
  int t = threadIdx.x;
  int wv = t >> 6, ln = t & 63;
  int wc = wv;                     // column stripe 0..3
  int row0 = blockIdx.x * 64;

  const float* aptr[4];
#pragma unroll
  for (int i = 0; i < 4; ++i) {
    int chunk = i * 4 + wv;
    int r = chunk * 4 + (ln >> 4);
    int gr = row0 + r;
    if (gr >= N_NODES) gr = N_NODES - 1;
    aptr[i] = &A[(long long)gr * DIN + (((ln & 15) ^ (r & 7)) << 2)];
  }
  const unsigned short* bptr[8];
#pragma unroll
  for (int i = 0; i < 8; ++i) {
    int chunk = i * 4 + wv;
    int r = chunk * 8 + (ln >> 3);
    bptr[i] = &Bb[(long long)r * DIN + (((ln & 7) ^ (r & 7)) << 3)];
  }

  f32x4 acc[4][4];
#pragma unroll
  for (int mi = 0; mi < 4; ++mi)
#pragma unroll
    for (int ni = 0; ni < 4; ++ni) acc[mi][ni] = (f32x4){0.f, 0.f, 0.f, 0.f};

  int g = ln >> 4;    // k-group 0..3
  int fr = ln & 15;

  for (int k0 = 0; k0 < DIN; k0 += 64) {
#pragma unroll
    for (int i = 0; i < 4; ++i)
      __builtin_amdgcn_global_load_lds(AS1(aptr[i] + k0),
                                       AS3(&As[(i * 4 + wv) * 256]), 16, 0, 0);
#pragma unroll
    for (int i = 0; i < 8; ++i)
      __builtin_amdgcn_global_load_lds(AS1(bptr[i] + k0),
                                       AS3(&Bs[(i * 4 + wv) * 512]), 16, 0, 0);
    __syncthreads();

#pragma unroll
    for (int kk = 0; kk < 2; ++kk) {
      short8 af[4], bfr[4];
#pragma unroll
      for (int mi = 0; mi < 4; ++mi) {
        int r = mi * 16 + fr;
        int s0 = kk * 8 + ((2 * g) ^ (r & 7));
        int s1 = kk * 8 + ((2 * g + 1) ^ (r & 7));
        f32x4 a0 = *(const f32x4*)&As[r * 64 + s0 * 4];
        f32x4 a1 = *(const f32x4*)&As[r * 64 + s1 * 4];
        u32x4 pk;
        pk.x = cvtpk(a0[0], a0[1]);
        pk.y = cvtpk(a0[2], a0[3]);
        pk.z = cvtpk(a1[0], a1[1]);
        pk.w = cvtpk(a1[2], a1[3]);
        af[mi] = __builtin_bit_cast(short8, pk);
      }
#pragma unroll
      for (int ni = 0; ni < 4; ++ni) {
        int c = wc * 64 + ni * 16 + fr;
        int slot = (kk * 4 + g) ^ (c & 7);
        bfr[ni] = *(const short8*)&Bs[c * 64 + slot * 8];
      }
#pragma unroll
      for (int mi = 0; mi < 4; ++mi)
#pragma unroll
        for (int ni = 0; ni < 4; ++ni)
          acc[mi][ni] = __builtin_amdgcn_mfma_f32_16x16x32_bf16(af[mi], bfr[ni], acc[mi][ni], 0, 0, 0);
    }
    __syncthreads();
  }

  int fq = ln >> 4;
  float ss[4][4];
#pragma unroll
  for (int mi = 0; mi < 4; ++mi)
#pragma unroll
    for (int j = 0; j < 4; ++j) ss[mi][j] = 0.f;

#pragma unroll
  for (int ni = 0; ni < 4; ++ni) {
    int colv = wc * 64 + ni * 16 + fr;
    float bv = bias[colv];
#pragma unroll
    for (int mi = 0; mi < 4; ++mi) {
#pragma unroll
      for (int j = 0; j < 4; ++j) {
        int row = row0 + mi * 16 + fq * 4 + j;
        unsigned short us = f2bf(fmaxf(acc[mi][ni][j] + bv, 0.f));
        if (row < N_NODES) C[(long long)row * HID + colv] = us;
        float v = bf2f(us);
        ss[mi][j] = fmaf(v, v, ss[mi][j]);
      }
    }
  }

#pragma unroll
  for (int mi = 0; mi < 4; ++mi)
#pragma unroll
    for (int j = 0; j < 4; ++j) {
      float s = ss[mi][j];
      s += __shfl_xor(s, 1);
      s += __shfl_xor(s, 2);
      s += __shfl_xor(s, 4);
      s += __shfl_xor(s, 8);
      ss[mi][j] = s;
    }
  float* redS = As;  // reuse A-tile LDS: [64 rows][4 waves]
  if (fr == 0) {
#pragma unroll
    for (int mi = 0; mi < 4; ++mi)
#pragma unroll
      for (int j = 0; j < 4; ++j)
        redS[(mi * 16 + fq * 4 + j) * 4 + wv] = ss[mi][j];
  }
  __syncthreads();
  if (t < 64) {
    int row = row0 + t;
    if (row < N_NODES) {
      float tot = redS[t * 4 + 0] + redS[t * 4 + 1] + redS[t * 4 + 2] + redS[t * 4 + 3];
      invn[row] = 1.0f / fmaxf(sqrtf(tot), 1e-12f);
    }
  }
}

// fused AGNN conv #1: 1 wave/node, 4 edge-groups x 16 lanes, 16 feats/lane.
// Exact r2 body + fused output-norm (invn_out, separate buffer).
__global__ __launch_bounds__(256) void convK(const unsigned short* __restrict__ hb,
                                             const float* __restrict__ invn,
                                             const int* __restrict__ row_ptr,
                                             const int* __restrict__ col,
                                             const float* __restrict__ beta_ptr,
                                             float* __restrict__ hout,
                                             unsigned short* __restrict__ hout_bf,
                                             float* __restrict__ invn_out) {
  int w = (blockIdx.x * 256 + threadIdx.x) >> 6;
  int lane = threadIdx.x & 63;
  if (w >= N_NODES) return;
  int g = lane >> 4;    // edge-group 0..3
  int sub = lane & 15;  // feature slice [sub*16, sub*16+16)
  float beta = beta_ptr ? beta_ptr[0] : 1.0f;
  float babs = fabsf(beta);

  const unsigned short* hrow = &hb[(long long)w * HID + sub * 16];
  short8 hia = *(const short8*)hrow;
  short8 hib = *(const short8*)(hrow + 8);
  float hi[16];
#pragma unroll
  for (int q = 0; q < 8; ++q) {
    hi[q] = bf2f((unsigned short)hia[q]);
    hi[8 + q] = bf2f((unsigned short)hib[q]);
  }
  float scale_i = invn[w] * beta;

  int e0 = row_ptr[w], e1 = row_ptr[w + 1];
  int nit = (e1 - e0 + 3) >> 2;
  float Z = 0.f;
  float acc[16];
#pragma unroll
  for (int q = 0; q < 16; ++q) acc[q] = 0.f;

  for (int it = 0; it < nit; ++it) {
    int ee = e0 + it * 4 + g;
    bool valid = ee < e1;
    int s = col[valid ? ee : (e1 - 1)];
    float is = invn[s];
    const unsigned short* hj = &hb[(long long)s * HID + sub * 16];
    short8 ja = *(const short8*)hj;
    short8 jb = *(const short8*)(hj + 8);
    float hjf[16];
#pragma unroll
    for (int q = 0; q < 8; ++q) {
      hjf[q] = bf2f((unsigned short)ja[q]);
      hjf[8 + q] = bf2f((unsigned short)jb[q]);
    }
    float p = 0.f;
#pragma unroll
    for (int q = 0; q < 16; ++q) p += hi[q] * hjf[q];
    p += __shfl_xor(p, 1);
    p += __shfl_xor(p, 2);
    p += __shfl_xor(p, 4);
    p += __shfl_xor(p, 8);
    float sc = p * scale_i * is;
    float wt = valid ? __expf(sc - babs) : 0.f;
    Z += wt;
#pragma unroll
    for (int q = 0; q < 16; ++q) acc[q] += wt * hjf[q];
  }

#pragma unroll
  for (int q = 0; q < 16; ++q) {
    acc[q] += __shfl_xor(acc[q], 16);
    acc[q] += __shfl_xor(acc[q], 32);
  }
  Z += __shfl_xor(Z, 16);
  Z += __shfl_xor(Z, 32);
  float r = 1.0f / Z;

  if (g == 0) {
    float* po = &hout[(long long)w * HID + sub * 16];
#pragma unroll
    for (int q4 = 0; q4 < 4; ++q4) {
      float4 o;
      o.x = acc[q4 * 4 + 0] * r;
      o.y = acc[q4 * 4 + 1] * r;
      o.z = acc[q4 * 4 + 2] * r;
      o.w = acc[q4 * 4 + 3] * r;
      *(float4*)&po[q4 * 4] = o;
    }
  } else if (g == 1 && hout_bf) {
    unsigned short* pb = &hout_bf[(long long)w * HID + sub * 16];
#pragma unroll
    for (int q4 = 0; q4 < 4; ++q4) {
      us4 ob;
      ob.x = f2bf(acc[q4 * 4 + 0] * r);
      ob.y = f2bf(acc[q4 * 4 + 1] * r);
      ob.z = f2bf(acc[q4 * 4 + 2] * r);
      ob.w = f2bf(acc[q4 * 4 + 3] * r);
      *(us4*)&pb[q4 * 4] = ob;
    }
  }

  if (invn_out) {
    float ss = 0.f;
#pragma unroll
    for (int q = 0; q < 16; ++q) {
      float v = bf2f(f2bf(acc[q] * r));
      ss = fmaf(v, v, ss);
    }
    ss += __shfl_xor(ss, 1);
    ss += __shfl_xor(ss, 2);
    ss += __shfl_xor(ss, 4);
    ss += __shfl_xor(ss, 8);
    if (lane == 0) invn_out[w] = 1.0f / fmaxf(sqrtf(ss), 1e-12f);
  }
}

// conv #2 + fused head GEMM (bf16 w2 from LDS) + log-softmax.
// Same gather body as convK; epilogue: lane (g,sub) computes 16-logit
// partials over its 16-feat slice (v_pk_fma_f32), shfl-allreduce over sub,
// lane ends holding logit c=lane; 64-lane max/sum -> log-softmax -> lsm.
// Grid covers N exactly (12500*4 waves) so the staging barrier is safe.
__global__ __launch_bounds__(256) void convHeadK(const unsigned short* __restrict__ hb,
                                                 const float* __restrict__ invn,
                                                 const int* __restrict__ row_ptr,
                                                 const int* __restrict__ col,
                                                 const float* __restrict__ beta_ptr,
                                                 const unsigned* __restrict__ w2b,
                                                 const float* __restrict__ b2,
                                                 float* __restrict__ hout,
                                                 float* __restrict__ lsm) {
  __shared__ unsigned w2s[NOUT * 128];  // 32 KB bf16-pair table
  int t = threadIdx.x;
#pragma unroll
  for (int i = 0; i < 32; ++i) w2s[i * 256 + t] = w2b[i * 256 + t];
  __syncthreads();

  int w = (blockIdx.x * 256 + t) >> 6;
  int lane = t & 63;
  int g = lane >> 4;
  int sub = lane & 15;
  float beta = beta_ptr[0];
  float babs = fabsf(beta);

  const unsigned short* hrow = &hb[(long long)w * HID + sub * 16];
  short8 hia = *(const short8*)hrow;
  short8 hib = *(const short8*)(hrow + 8);
  float hi[16];
#pragma unroll
  for (int q = 0; q < 8; ++q) {
    hi[q] = bf2f((unsigned short)hia[q]);
    hi[8 + q] = bf2f((unsigned short)hib[q]);
  }
  float scale_i = invn[w] * beta;

  int e0 = row_ptr[w], e1 = row_ptr[w + 1];
  int nit = (e1 - e0 + 3) >> 2;
  float Z = 0.f;
  float acc[16];
#pragma unroll
  for (int q = 0; q < 16; ++q) acc[q] = 0.f;

  for (int it = 0; it < nit; ++it) {
    int ee = e0 + it * 4 + g;
    bool valid = ee < e1;
    int s = col[valid ? ee : (e1 - 1)];
    float is = invn[s];
    const unsigned short* hj = &hb[(long long)s * HID + sub * 16];
    short8 ja = *(const short8*)hj;
    short8 jb = *(const short8*)(hj + 8);
    float hjf[16];
#pragma unroll
    for (int q = 0; q < 8; ++q) {
      hjf[q] = bf2f((unsigned short)ja[q]);
      hjf[8 + q] = bf2f((unsigned short)jb[q]);
    }
    float p = 0.f;
#pragma unroll
    for (int q = 0; q < 16; ++q) p += hi[q] * hjf[q];
    p += __shfl_xor(p, 1);
    p += __shfl_xor(p, 2);
    p += __shfl_xor(p, 4);
    p += __shfl_xor(p, 8);
    float sc = p * scale_i * is;
    float wt = valid ? __expf(sc - babs) : 0.f;
    Z += wt;
#pragma unroll
    for (int q = 0; q < 16; ++q) acc[q] += wt * hjf[q];
  }

#pragma unroll
  for (int q = 0; q < 16; ++q) {
    acc[q] += __shfl_xor(acc[q], 16);
    acc[q] += __shfl_xor(acc[q], 32);
  }
  Z += __shfl_xor(Z, 16);
  Z += __shfl_xor(Z, 32);
  float r = 1.0f / Z;

  if (g == 0) {  // z2 fp32 output row
    float* po = &hout[(long long)w * HID + sub * 16];
#pragma unroll
    for (int q4 = 0; q4 < 4; ++q4) {
      float4 o;
      o.x = acc[q4 * 4 + 0] * r;
      o.y = acc[q4 * 4 + 1] * r;
      o.z = acc[q4 * 4 + 2] * r;
      o.w = acc[q4 * 4 + 3] * r;
      *(float4*)&po[q4 * 4] = o;
    }
  }

  // ---- fused head: logits[c] = z2[w] . w2[c] + b2[c], then log-softmax ----
  f32x2 zp[8];
#pragma unroll
  for (int j2 = 0; j2 < 8; ++j2)
    zp[j2] = (f32x2){acc[2 * j2] * r, acc[2 * j2 + 1] * r};

  float p[16];
#pragma unroll
  for (int idx = 0; idx < 16; ++idx) {
    int c = g * 16 + idx;
    const unsigned* wrow = &w2s[c * 128 + sub * 8];
    f32x2 d = (f32x2){0.f, 0.f};
#pragma unroll
    for (int j2 = 0; j2 < 8; ++j2) d = FMA2(bfpair(wrow[j2]), zp[j2], d);
    p[idx] = d.x + d.y;
  }
  // allreduce over the 16 sub-lanes within each g-group
#pragma unroll
  for (int m = 1; m <= 8; m <<= 1) {
#pragma unroll
    for (int idx = 0; idx < 16; ++idx) p[idx] += __shfl_xor(p[idx], m);
  }
  // lane holds logit c = g*16 + sub = lane (static select, no scratch)
  float logit = 0.f;
#pragma unroll
  for (int idx = 0; idx < 16; ++idx)
    if (sub == idx) logit = p[idx];
  logit += b2[lane];

  float mx = logit;
#pragma unroll
  for (int off = 1; off <= 32; off <<= 1) mx = fmaxf(mx, __shfl_xor(mx, off));
  float ex = __expf(logit - mx);
  float se = ex;
#pragma unroll
  for (int off = 1; off <= 32; off <<= 1) se += __shfl_xor(se, off);
  lsm[(long long)w * NOUT + lane] = logit - mx - __logf(se);
}

extern "C" void kernel_launch(void* const* d_in, const int* in_sizes, int n_in,
                              void* d_out, int out_size, void* d_ws, size_t ws_size,
                              hipStream_t stream) {
  (void)in_sizes; (void)n_in; (void)out_size; (void)ws_size;
  const float* x = (const float*)d_in[0];
  const void* ei = d_in[1];
  const float* w1 = (const float*)d_in[2];
  const float* b1 = (const float*)d_in[3];
  const float* beta2 = (const float*)d_in[4];
  const float* w2 = (const float*)d_in[5];
  const float* b2 = (const float*)d_in[6];

  float* z1 = (float*)d_out;                       // [N, 256]
  float* z2 = z1 + (size_t)N_NODES * HID;          // [N, 256]
  float* lsm = z2 + (size_t)N_NODES * HID;         // [N, 64]

  unsigned short* h_bf = (unsigned short*)d_ws;             // [N,256] bf16
  unsigned short* z1_bf = h_bf + (size_t)N_NODES * HID;     // [N,256] bf16
  float* invn = (float*)(z1_bf + (size_t)N_NODES * HID);    // [N]
  int* row_ptr = (int*)(invn + N_NODES);                    // [N+1]
  int* cursor = row_ptr + N_NODES + 1;                      // [N]
  int* colv = cursor + N_NODES;                             // [ETOT]
  int* bsums = colv + ETOT;                                 // [<=64]
  int* flag = bsums + 64;                                   // [1]
  unsigned short* wb = (unsigned short*)(flag + 4);         // [256,512] bf16 w1
  float* invn2 = (float*)(wb + (size_t)HID * DIN);          // [N]
  unsigned* w2b = (unsigned*)(invn2 + N_NODES);             // [64*128] bf16 pairs

  int nScan = (N_NODES + SCAN_CHUNK - 1) / SCAN_CHUNK;

  initK<<<(N_NODES + 255) / 256, 256, 0, stream>>>(ei, cursor, flag, w1, wb, w2, w2b);

  gemm1MF<<<(N_NODES + 63) / 64, 256, 0, stream>>>(x, wb, b1, h_bf, invn);

  histK<<<(N_EDGES + 255) / 256, 256, 0, stream>>>(ei, flag, cursor);
  scan1K<<<nScan, 256, 0, stream>>>(cursor, row_ptr, bsums);
  scan3K<<<(N_NODES + 255) / 256, 256, 0, stream>>>(row_ptr, bsums, cursor);
  scatterK<<<(N_EDGES + N_NODES + 255) / 256, 256, 0, stream>>>(ei, flag, cursor, colv);

  convK<<<(N_NODES + 3) / 4, 256, 0, stream>>>(h_bf, invn, row_ptr, colv, nullptr, z1, z1_bf, invn2);
  convHeadK<<<(N_NODES + 3) / 4, 256, 0, stream>>>(z1_bf, invn2, row_ptr, colv, beta2, w2b, b2, z2, lsm);
}

// Round 11
// 310.401 us; speedup vs baseline: 1.1485x; 1.1485x over previous
//
#include <hip/hip_runtime.h>

#define N_NODES 50000
#define N_EDGES 800000
#define ETOT (N_EDGES + N_NODES)
#define DIN 512
#define HID 256
#define NOUT 64
#define SCAN_CHUNK 2048
#define GEMM_BLKS ((N_NODES + 63) / 64)

typedef __attribute__((ext_vector_type(8))) short short8;
typedef __attribute__((ext_vector_type(4))) float f32x4;
typedef __attribute__((ext_vector_type(4))) unsigned short us4;
typedef __attribute__((ext_vector_type(4))) unsigned int u32x4;

// float -> bf16 bits, round-to-nearest-even
__device__ __forceinline__ unsigned short f2bf(float f) {
  union { float f; unsigned u; } x; x.f = f;
  unsigned r = x.u + 0x7fff + ((x.u >> 16) & 1);
  return (unsigned short)(r >> 16);
}
__device__ __forceinline__ float bf2f(unsigned short b) {
  return __uint_as_float(((unsigned)b) << 16);
}
// packed RNE convert: {lo: bf16(a), hi: bf16(b)} in one VALU inst
__device__ __forceinline__ unsigned cvtpk(float a, float b) {
  unsigned r;
  asm("v_cvt_pk_bf16_f32 %0, %1, %2" : "=v"(r) : "v"(a), "v"(b));
  return r;
}

// address-space casts for global_load_lds
#define AS1(p) ((const __attribute__((address_space(1))) unsigned int*)(p))
#define AS3(p) ((__attribute__((address_space(3))) unsigned int*)(p))

// ---------------- edge index decode (int32 vs int64 hedge) ----------------
__device__ __forceinline__ int edge_at(const void* ei, long long idx, int is32) {
  if (is32) return ((const int*)ei)[idx];
  return (int)((const long long*)ei)[idx];
}

// cursor[i]=1 (self-loop pre-count) + dtype detect + w1 -> bf16 convert.
__global__ void initK(const void* ei, int* cursor, int* flag,
                      const float* __restrict__ w1, unsigned short* __restrict__ wb) {
  int i = blockIdx.x * blockDim.x + threadIdx.x;
  if (i < N_NODES) cursor[i] = 1;
  if (i < (HID * DIN) / 8) {  // 16384 chunks of 8 floats
    const float* src = w1 + i * 8;
    float4 v0 = ((const float4*)src)[0];
    float4 v1 = ((const float4*)src)[1];
    short8 s;
    s[0] = f2bf(v0.x); s[1] = f2bf(v0.y); s[2] = f2bf(v0.z); s[3] = f2bf(v0.w);
    s[4] = f2bf(v1.x); s[5] = f2bf(v1.y); s[6] = f2bf(v1.z); s[7] = f2bf(v1.w);
    *(short8*)(wb + i * 8) = s;
  }
  if (blockIdx.x == 0 && threadIdx.x < 64) {
    int lane = threadIdx.x;
    bool bad = false;
#pragma unroll
    for (int j = 0; j < 32; ++j) {
      long long v = ((const long long*)ei)[lane * 32 + j];
      bad |= (v < 0 || v >= N_NODES);
    }
    bool anybad = __any(bad);
    if (lane == 0) *flag = anybad ? 1 : 0;
  }
}

// ---------------- exclusive scan over counts -> row_ptr ----------------
__global__ void scan1K(const int* counts, int* excl, int* bsums) {
  __shared__ int sdata[256];
  int base = blockIdx.x * SCAN_CHUNK;
  int t = threadIdx.x;
  int local[8];
  int sum = 0;
#pragma unroll
  for (int j = 0; j < 8; ++j) {
    int idx = base + t * 8 + j;
    int v = (idx < N_NODES) ? counts[idx] : 0;
    local[j] = sum;
    sum += v;
  }
  sdata[t] = sum;
  __syncthreads();
  for (int off = 1; off < 256; off <<= 1) {
    int v = (t >= off) ? sdata[t - off] : 0;
    __syncthreads();
    sdata[t] += v;
    __syncthreads();
  }
  int texcl = (t == 0) ? 0 : sdata[t - 1];
#pragma unroll
  for (int j = 0; j < 8; ++j) {
    int idx = base + t * 8 + j;
    if (idx < N_NODES) excl[idx] = texcl + local[j];
  }
  if (t == 255) bsums[blockIdx.x] = sdata[255];
}

// scan3: add inline prefix of raw bsums (<=25 entries, wave-uniform loop).
__global__ void scan3K(int* row_ptr, const int* bsums, int* cursor) {
  int i = blockIdx.x * blockDim.x + threadIdx.x;
  if (i < N_NODES) {
    int nb = i >> 11;
    int pre = 0;
    for (int b = 0; b < nb; ++b) pre += bsums[b];
    int v = row_ptr[i] + pre;
    row_ptr[i] = v;
    cursor[i] = v;
    if (i == 0) row_ptr[N_NODES] = ETOT;
  }
}

__global__ void scatterK(const void* ei, const int* flag, int* cursor, int* col) {
  int e = blockIdx.x * blockDim.x + threadIdx.x;
  if (e < N_EDGES) {
    int f = *flag;
    int s = edge_at(ei, e, f);
    int d = edge_at(ei, (long long)N_EDGES + e, f);
    int pos = atomicAdd(&cursor[d], 1);
    col[pos] = s;
  } else if (e < N_EDGES + N_NODES) {
    int i = e - N_EDGES;
    int pos = atomicAdd(&cursor[i], 1);
    col[pos] = i;
  }
}

// ------- GEMM1 (+ fused row-norm) ∥ histK, grid-partitioned ----------------
// blocks [0, GEMM_BLKS): r9-proven GEMM body (BM=64, BN=256, x read once,
// A fp32 swizzle 2-way-free, B bf16 r2-proven 0-conflict, fused invn).
// blocks [GEMM_BLKS, +3125): edge histogram atomics (no LDS, no barrier) —
// overlapped under the GEMM instead of a separate serialized dispatch.
__global__ __launch_bounds__(256) void gemmHistK(const float* __restrict__ A,
                                                 const unsigned short* __restrict__ Bb,
                                                 const float* __restrict__ bias,
                                                 unsigned short* __restrict__ C,
                                                 float* __restrict__ invn,
                                                 const void* __restrict__ ei,
                                                 const int* __restrict__ flag,
                                                 int* __restrict__ cursor) {
  __shared__ float As[64 * 64];    // 16 KB
  __shared__ short Bs[256 * 64];   // 32 KB
  int t = threadIdx.x;

  if (blockIdx.x >= GEMM_BLKS) {  // ---- hist branch: block-uniform, no LDS ----
    int e = (blockIdx.x - GEMM_BLKS) * 256 + t;
    if (e < N_EDGES) {
      int f = *flag;
      int d = edge_at(ei, (long long)N_EDGES + e, f);
      atomicAdd(&cursor[d], 1);
    }
    return;
  }

  int wv = t >> 6, ln = t & 63;
  int wc = wv;                     // column stripe 0..3
  int row0 = blockIdx.x * 64;

  const float* aptr[4];
#pragma unroll
  for (int i = 0; i < 4; ++i) {
    int chunk = i * 4 + wv;
    int r = chunk * 4 + (ln >> 4);
    int gr = row0 + r;
    if (gr >= N_NODES) gr = N_NODES - 1;
    aptr[i] = &A[(long long)gr * DIN + (((ln & 15) ^ (r & 7)) << 2)];
  }
  const unsigned short* bptr[8];
#pragma unroll
  for (int i = 0; i < 8; ++i) {
    int chunk = i * 4 + wv;
    int r = chunk * 8 + (ln >> 3);
    bptr[i] = &Bb[(long long)r * DIN + (((ln & 7) ^ (r & 7)) << 3)];
  }

  f32x4 acc[4][4];
#pragma unroll
  for (int mi = 0; mi < 4; ++mi)
#pragma unroll
    for (int ni = 0; ni < 4; ++ni) acc[mi][ni] = (f32x4){0.f, 0.f, 0.f, 0.f};

  int g = ln >> 4;    // k-group 0..3
  int fr = ln & 15;

  for (int k0 = 0; k0 < DIN; k0 += 64) {
#pragma unroll
    for (int i = 0; i < 4; ++i)
      __builtin_amdgcn_global_load_lds(AS1(aptr[i] + k0),
                                       AS3(&As[(i * 4 + wv) * 256]), 16, 0, 0);
#pragma unroll
    for (int i = 0; i < 8; ++i)
      __builtin_amdgcn_global_load_lds(AS1(bptr[i] + k0),
                                       AS3(&Bs[(i * 4 + wv) * 512]), 16, 0, 0);
    __syncthreads();

#pragma unroll
    for (int kk = 0; kk < 2; ++kk) {
      short8 af[4], bfr[4];
#pragma unroll
      for (int mi = 0; mi < 4; ++mi) {
        int r = mi * 16 + fr;
        int s0 = kk * 8 + ((2 * g) ^ (r & 7));
        int s1 = kk * 8 + ((2 * g + 1) ^ (r & 7));
        f32x4 a0 = *(const f32x4*)&As[r * 64 + s0 * 4];
        f32x4 a1 = *(const f32x4*)&As[r * 64 + s1 * 4];
        u32x4 pk;
        pk.x = cvtpk(a0[0], a0[1]);
        pk.y = cvtpk(a0[2], a0[3]);
        pk.z = cvtpk(a1[0], a1[1]);
        pk.w = cvtpk(a1[2], a1[3]);
        af[mi] = __builtin_bit_cast(short8, pk);
      }
#pragma unroll
      for (int ni = 0; ni < 4; ++ni) {
        int c = wc * 64 + ni * 16 + fr;
        int slot = (kk * 4 + g) ^ (c & 7);
        bfr[ni] = *(const short8*)&Bs[c * 64 + slot * 8];
      }
#pragma unroll
      for (int mi = 0; mi < 4; ++mi)
#pragma unroll
        for (int ni = 0; ni < 4; ++ni)
          acc[mi][ni] = __builtin_amdgcn_mfma_f32_16x16x32_bf16(af[mi], bfr[ni], acc[mi][ni], 0, 0, 0);
    }
    __syncthreads();
  }

  int fq = ln >> 4;
  float ss[4][4];
#pragma unroll
  for (int mi = 0; mi < 4; ++mi)
#pragma unroll
    for (int j = 0; j < 4; ++j) ss[mi][j] = 0.f;

#pragma unroll
  for (int ni = 0; ni < 4; ++ni) {
    int colv = wc * 64 + ni * 16 + fr;
    float bv = bias[colv];
#pragma unroll
    for (int mi = 0; mi < 4; ++mi) {
#pragma unroll
      for (int j = 0; j < 4; ++j) {
        int row = row0 + mi * 16 + fq * 4 + j;
        unsigned short us = f2bf(fmaxf(acc[mi][ni][j] + bv, 0.f));
        if (row < N_NODES) C[(long long)row * HID + colv] = us;
        float v = bf2f(us);
        ss[mi][j] = fmaf(v, v, ss[mi][j]);
      }
    }
  }

#pragma unroll
  for (int mi = 0; mi < 4; ++mi)
#pragma unroll
    for (int j = 0; j < 4; ++j) {
      float s = ss[mi][j];
      s += __shfl_xor(s, 1);
      s += __shfl_xor(s, 2);
      s += __shfl_xor(s, 4);
      s += __shfl_xor(s, 8);
      ss[mi][j] = s;
    }
  float* redS = As;  // reuse A-tile LDS: [64 rows][4 waves]
  if (fr == 0) {
#pragma unroll
    for (int mi = 0; mi < 4; ++mi)
#pragma unroll
      for (int j = 0; j < 4; ++j)
        redS[(mi * 16 + fq * 4 + j) * 4 + wv] = ss[mi][j];
  }
  __syncthreads();
  if (t < 64) {
    int row = row0 + t;
    if (row < N_NODES) {
      float tot = redS[t * 4 + 0] + redS[t * 4 + 1] + redS[t * 4 + 2] + redS[t * 4 + 3];
      invn[row] = 1.0f / fmaxf(sqrtf(tot), 1e-12f);
    }
  }
}

// fused AGNN conv: 1 wave/node, 4 edge-groups x 16 lanes, 16 feats/lane.
// Exact r2 body (measured floor ~72.4 us; gather-BW-bound). Optional fused
// output-norm writes invn_out (separate buffer).
__global__ __launch_bounds__(256) void convK(const unsigned short* __restrict__ hb,
                                             const float* __restrict__ invn,
                                             const int* __restrict__ row_ptr,
                                             const int* __restrict__ col,
                                             const float* __restrict__ beta_ptr,
                                             float* __restrict__ hout,
                                             unsigned short* __restrict__ hout_bf,
                                             float* __restrict__ invn_out) {
  int w = (blockIdx.x * 256 + threadIdx.x) >> 6;
  int lane = threadIdx.x & 63;
  if (w >= N_NODES) return;
  int g = lane >> 4;    // edge-group 0..3
  int sub = lane & 15;  // feature slice [sub*16, sub*16+16)
  float beta = beta_ptr ? beta_ptr[0] : 1.0f;
  float babs = fabsf(beta);

  const unsigned short* hrow = &hb[(long long)w * HID + sub * 16];
  short8 hia = *(const short8*)hrow;
  short8 hib = *(const short8*)(hrow + 8);
  float hi[16];
#pragma unroll
  for (int q = 0; q < 8; ++q) {
    hi[q] = bf2f((unsigned short)hia[q]);
    hi[8 + q] = bf2f((unsigned short)hib[q]);
  }
  float scale_i = invn[w] * beta;

  int e0 = row_ptr[w], e1 = row_ptr[w + 1];
  int nit = (e1 - e0 + 3) >> 2;
  float Z = 0.f;
  float acc[16];
#pragma unroll
  for (int q = 0; q < 16; ++q) acc[q] = 0.f;

  for (int it = 0; it < nit; ++it) {
    int ee = e0 + it * 4 + g;
    bool valid = ee < e1;
    int s = col[valid ? ee : (e1 - 1)];
    float is = invn[s];
    const unsigned short* hj = &hb[(long long)s * HID + sub * 16];
    short8 ja = *(const short8*)hj;
    short8 jb = *(const short8*)(hj + 8);
    float hjf[16];
#pragma unroll
    for (int q = 0; q < 8; ++q) {
      hjf[q] = bf2f((unsigned short)ja[q]);
      hjf[8 + q] = bf2f((unsigned short)jb[q]);
    }
    float p = 0.f;
#pragma unroll
    for (int q = 0; q < 16; ++q) p += hi[q] * hjf[q];
    p += __shfl_xor(p, 1);
    p += __shfl_xor(p, 2);
    p += __shfl_xor(p, 4);
    p += __shfl_xor(p, 8);
    float sc = p * scale_i * is;
    float wt = valid ? __expf(sc - babs) : 0.f;
    Z += wt;
#pragma unroll
    for (int q = 0; q < 16; ++q) acc[q] += wt * hjf[q];
  }

  // cross-group combine (4 partial vectors -> full sums in all lanes)
#pragma unroll
  for (int q = 0; q < 16; ++q) {
    acc[q] += __shfl_xor(acc[q], 16);
    acc[q] += __shfl_xor(acc[q], 32);
  }
  Z += __shfl_xor(Z, 16);
  Z += __shfl_xor(Z, 32);
  float r = 1.0f / Z;

  if (g == 0) {  // fp32 output, 64B/lane over 16 lanes = full 1KB row
    float* po = &hout[(long long)w * HID + sub * 16];
#pragma unroll
    for (int q4 = 0; q4 < 4; ++q4) {
      float4 o;
      o.x = acc[q4 * 4 + 0] * r;
      o.y = acc[q4 * 4 + 1] * r;
      o.z = acc[q4 * 4 + 2] * r;
      o.w = acc[q4 * 4 + 3] * r;
      *(float4*)&po[q4 * 4] = o;
    }
  } else if (g == 1 && hout_bf) {  // bf16 copy for next conv
    unsigned short* pb = &hout_bf[(long long)w * HID + sub * 16];
#pragma unroll
    for (int q4 = 0; q4 < 4; ++q4) {
      us4 ob;
      ob.x = f2bf(acc[q4 * 4 + 0] * r);
      ob.y = f2bf(acc[q4 * 4 + 1] * r);
      ob.z = f2bf(acc[q4 * 4 + 2] * r);
      ob.w = f2bf(acc[q4 * 4 + 3] * r);
      *(us4*)&pb[q4 * 4] = ob;
    }
  }

  // fused norm of the (bf16-rounded) output row -> invn for the next conv.
  if (invn_out) {
    float ss = 0.f;
#pragma unroll
    for (int q = 0; q < 16; ++q) {
      float v = bf2f(f2bf(acc[q] * r));
      ss = fmaf(v, v, ss);
    }
    ss += __shfl_xor(ss, 1);
    ss += __shfl_xor(ss, 2);
    ss += __shfl_xor(ss, 4);
    ss += __shfl_xor(ss, 8);
    if (lane == 0) invn_out[w] = 1.0f / fmaxf(sqrtf(ss), 1e-12f);
  }
}

// ---------------- head: tiled GEMM (64x64 tile, K=256) + fused log-softmax ----
__global__ __launch_bounds__(256) void headK2(const float* __restrict__ Z,
                                              const float* __restrict__ W,
                                              const float* __restrict__ bias,
                                              float* __restrict__ out) {
  __shared__ float smem[2 * 32 * 68];
  float* As = smem;
  float* Bs = smem + 32 * 68;
  int t = threadIdx.x;
  int tx = t & 15, ty = t >> 4;
  int row0 = blockIdx.x * 64;
  float acc[4][4] = {};
  int lr = t >> 3;
  int lc4 = t & 7;

  for (int k0 = 0; k0 < HID; k0 += 32) {
#pragma unroll
    for (int rr = 0; rr < 64; rr += 32) {
      int gr = row0 + lr + rr;
      float4 va = (gr < N_NODES)
                      ? *(const float4*)&Z[(long long)gr * HID + k0 + lc4 * 4]
                      : make_float4(0.f, 0.f, 0.f, 0.f);
      As[(lc4 * 4 + 0) * 68 + lr + rr] = va.x;
      As[(lc4 * 4 + 1) * 68 + lr + rr] = va.y;
      As[(lc4 * 4 + 2) * 68 + lr + rr] = va.z;
      As[(lc4 * 4 + 3) * 68 + lr + rr] = va.w;
      int gc = lr + rr;
      float4 vb = *(const float4*)&W[(long long)gc * HID + k0 + lc4 * 4];
      Bs[(lc4 * 4 + 0) * 68 + lr + rr] = vb.x;
      Bs[(lc4 * 4 + 1) * 68 + lr + rr] = vb.y;
      Bs[(lc4 * 4 + 2) * 68 + lr + rr] = vb.z;
      Bs[(lc4 * 4 + 3) * 68 + lr + rr] = vb.w;
    }
    __syncthreads();
#pragma unroll
    for (int kk = 0; kk < 32; ++kk) {
      float4 a4 = *(const float4*)&As[kk * 68 + ty * 4];
      float4 b4 = *(const float4*)&Bs[kk * 68 + tx * 4];
      acc[0][0] += a4.x * b4.x; acc[0][1] += a4.x * b4.y; acc[0][2] += a4.x * b4.z; acc[0][3] += a4.x * b4.w;
      acc[1][0] += a4.y * b4.x; acc[1][1] += a4.y * b4.y; acc[1][2] += a4.y * b4.z; acc[1][3] += a4.y * b4.w;
      acc[2][0] += a4.z * b4.x; acc[2][1] += a4.z * b4.y; acc[2][2] += a4.z * b4.z; acc[2][3] += a4.z * b4.w;
      acc[3][0] += a4.w * b4.x; acc[3][1] += a4.w * b4.y; acc[3][2] += a4.w * b4.z; acc[3][3] += a4.w * b4.w;
    }
    __syncthreads();
  }

  float* ls = smem;
  float4 bv = *(const float4*)&bias[tx * 4];
#pragma unroll
  for (int r = 0; r < 4; ++r) {
    int lrow = ty * 4 + r;
    ls[lrow * 65 + tx * 4 + 0] = acc[r][0] + bv.x;
    ls[lrow * 65 + tx * 4 + 1] = acc[r][1] + bv.y;
    ls[lrow * 65 + tx * 4 + 2] = acc[r][2] + bv.z;
    ls[lrow * 65 + tx * 4 + 3] = acc[r][3] + bv.w;
  }
  __syncthreads();

  int wid = t >> 6, lane = t & 63;
#pragma unroll
  for (int rr2 = wid; rr2 < 64; rr2 += 4) {
    int node = row0 + rr2;
    if (node < N_NODES) {
      float v = ls[rr2 * 65 + lane];
      float mx = v;
#pragma unroll
      for (int off = 32; off >= 1; off >>= 1) mx = fmaxf(mx, __shfl_xor(mx, off));
      float ex = __expf(v - mx);
      float se = ex;
#pragma unroll
      for (int off = 32; off >= 1; off >>= 1) se += __shfl_xor(se, off);
      out[(long long)node * NOUT + lane] = v - mx - __logf(se);
    }
  }
}

extern "C" void kernel_launch(void* const* d_in, const int* in_sizes, int n_in,
                              void* d_out, int out_size, void* d_ws, size_t ws_size,
                              hipStream_t stream) {
  (void)in_sizes; (void)n_in; (void)out_size; (void)ws_size;
  const float* x = (const float*)d_in[0];
  const void* ei = d_in[1];
  const float* w1 = (const float*)d_in[2];
  const float* b1 = (const float*)d_in[3];
  const float* beta2 = (const float*)d_in[4];
  const float* w2 = (const float*)d_in[5];
  const float* b2 = (const float*)d_in[6];

  float* z1 = (float*)d_out;                       // [N, 256]
  float* z2 = z1 + (size_t)N_NODES * HID;          // [N, 256]
  float* lsm = z2 + (size_t)N_NODES * HID;         // [N, 64]

  unsigned short* h_bf = (unsigned short*)d_ws;             // [N,256] bf16
  unsigned short* z1_bf = h_bf + (size_t)N_NODES * HID;     // [N,256] bf16
  float* invn = (float*)(z1_bf + (size_t)N_NODES * HID);    // [N]
  int* row_ptr = (int*)(invn + N_NODES);                    // [N+1]
  int* cursor = row_ptr + N_NODES + 1;                      // [N]
  int* colv = cursor + N_NODES;                             // [ETOT]
  int* bsums = colv + ETOT;                                 // [<=64]
  int* flag = bsums + 64;                                   // [1]
  unsigned short* wb = (unsigned short*)(flag + 4);         // [256,512] bf16 w1
  float* invn2 = (float*)(wb + (size_t)HID * DIN);          // [N]

  int nScan = (N_NODES + SCAN_CHUNK - 1) / SCAN_CHUNK;
  int histBlks = (N_EDGES + 255) / 256;

  initK<<<(N_NODES + 255) / 256, 256, 0, stream>>>(ei, cursor, flag, w1, wb);

  gemmHistK<<<GEMM_BLKS + histBlks, 256, 0, stream>>>(x, wb, b1, h_bf, invn,
                                                      ei, flag, cursor);

  scan1K<<<nScan, 256, 0, stream>>>(cursor, row_ptr, bsums);
  scan3K<<<(N_NODES + 255) / 256, 256, 0, stream>>>(row_ptr, bsums, cursor);
  scatterK<<<(N_EDGES + N_NODES + 255) / 256, 256, 0, stream>>>(ei, flag, cursor, colv);

  convK<<<(N_NODES + 3) / 4, 256, 0, stream>>>(h_bf, invn, row_ptr, colv, nullptr, z1, z1_bf, invn2);
  convK<<<(N_NODES + 3) / 4, 256, 0, stream>>>(z1_bf, invn2, row_ptr, colv, beta2, z2, nullptr, nullptr);

  headK2<<<(N_NODES + 63) / 64, 256, 0, stream>>>(z2, w2, b2, lsm);
}